// Round 1
// baseline (644.752 us; speedup 1.0000x reference)
//
#include <hip/hip_runtime.h>
#include <math.h>

// sources: [4][32][512][512] fp32, kernels: [12][3][3] fp32, out: same as sources
// out_i = s_i - sum_j [ conv(s_j, kc_ij) + conv((s_j^0.5 * s_i)^(2/3), ki_ij) ]
//
// Key identity: with a = v^(1/3):  s = a^3,  (s_j^0.5 * s_i)^(2/3) = a_j * a_i^2.
// => stage ONLY a in LDS (halves LDS -> 8 blocks/CU), replace the per-pair
//    exp2(fma) (108 exp2/thread) with multiplies, and reconstruct raw values
//    as a^3 where needed (conv first term, output center).
// Edge sweep (0,1),(1,2),(2,3): each edge computes both directed pairs from
// one pair of row-windows; outputs stored from registers as soon as complete.

#define NCH  4
#define NIMG 32
#define HH   512
#define WW   512

#define TW   64
#define TH   16
#define HTWU 66            // used halo width
#define HTW  68            // padded stride (272 B, 16B-aligned rows)
#define HTH  18

#if __has_builtin(__builtin_amdgcn_exp2f)
#define EXP2(x) __builtin_amdgcn_exp2f(x)
#else
#define EXP2(x) exp2f(x)
#endif
#if __has_builtin(__builtin_amdgcn_logf)
#define LOG2(x) __builtin_amdgcn_logf(x)
#else
#define LOG2(x) __log2f(x)
#endif

__device__ __forceinline__ void load_row6(const float* __restrict__ row, float w[6]) {
    const float4 a = *(const float4*)row;          // ds_read_b128 (16B aligned)
    const float2 b = *(const float2*)(row + 4);    // ds_read_b64
    w[0] = a.x; w[1] = a.y; w[2] = a.z; w[3] = a.w; w[4] = b.x; w[5] = b.y;
}

// Edge between channels x and y = x+1 (a-values in Sx, Sy).
//   accX += conv(a_y^3, ker[KCX]) + conv(a_x^2 * a_y, ker[KIX])   (i=x, j=y)
//   accY += conv(a_x^3, ker[KCY]) + conv(a_y^2 * a_x, ker[KIY])   (i=y, j=x)
// cx/cy receive the center-row a values (cols tx4+1..tx4+4) for the epilogue.
template<int KCX, int KIX, int KCY, int KIY>
__device__ __forceinline__ void edge_conv(
    const float (*Sx)[HTW], const float (*Sy)[HTW],
    int ty, int tx4, const float* __restrict__ ker,
    float accX[4], float accY[4], float cx[4], float cy[4])
{
    #pragma unroll
    for (int r = 0; r < 3; ++r) {
        float ax[6], ay[6];
        load_row6(&Sx[ty + r][tx4], ax);
        load_row6(&Sy[ty + r][tx4], ay);
        if (r == 1) {
            #pragma unroll
            for (int q = 0; q < 4; ++q) { cx[q] = ax[q + 1]; cy[q] = ay[q + 1]; }
        }
        float ax2[6], ay2[6];
        #pragma unroll
        for (int q = 0; q < 6; ++q) { ax2[q] = ax[q] * ax[q]; ay2[q] = ay[q] * ay[q]; }

        // direction i=x (neighbor j=y): raw_y = ay^3, inter = ax^2 * ay
        {
            float w[6], t[6];
            #pragma unroll
            for (int q = 0; q < 6; ++q) { w[q] = ay2[q] * ay[q]; t[q] = ax2[q] * ay[q]; }
            #pragma unroll
            for (int q = 0; q < 4; ++q) {
                float s = accX[q];
                #pragma unroll
                for (int dx = 0; dx < 3; ++dx) {
                    s = fmaf(w[q + dx], ker[KCX * 9 + r * 3 + dx], s);
                    s = fmaf(t[q + dx], ker[KIX * 9 + r * 3 + dx], s);
                }
                accX[q] = s;
            }
        }
        // direction i=y (neighbor j=x): raw_x = ax^3, inter = ay^2 * ax
        {
            float w[6], t[6];
            #pragma unroll
            for (int q = 0; q < 6; ++q) { w[q] = ax2[q] * ax[q]; t[q] = ay2[q] * ax[q]; }
            #pragma unroll
            for (int q = 0; q < 4; ++q) {
                float s = accY[q];
                #pragma unroll
                for (int dx = 0; dx < 3; ++dx) {
                    s = fmaf(w[q + dx], ker[KCY * 9 + r * 3 + dx], s);
                    s = fmaf(t[q + dx], ker[KIY * 9 + r * 3 + dx], s);
                }
                accY[q] = s;
            }
        }
    }
}

// out = center^3 - bleed, dwordx4 store
__device__ __forceinline__ void store_out(float* __restrict__ p,
                                          const float c[4], const float a[4]) {
    float4 o;
    o.x = c[0] * c[0] * c[0] - a[0];
    o.y = c[1] * c[1] * c[1] - a[1];
    o.z = c[2] * c[2] * c[2] - a[2];
    o.w = c[3] * c[3] * c[3] - a[3];
    *(float4*)p = o;
}

__global__ __launch_bounds__(256, 8) void bleed_kernel(
    const float* __restrict__ src,   // [4][32][512][512]
    const float* __restrict__ ker,   // [12][3][3]
    float* __restrict__ out)
{
    __shared__ __align__(16) float sA[NCH][HTH][HTW];  // a = v^(1/3)

    const int tid    = threadIdx.x;
    const int tx     = tid & 15;      // col group: cols 4*tx .. 4*tx+3
    const int ty     = tid >> 4;      // row 0..15
    const int tx4    = tx * 4;
    const int tile_x = blockIdx.x * TW;
    const int tile_y = blockIdx.y * TH;
    const int n      = blockIdx.z;    // image index

    const size_t plane = (size_t)HH * WW;

    // ---- stage a = v^(1/3) for all 4 channels, zero-padded halo ----
    // 64-lane rows: lane lx covers col lx; lanes 0,1 also cover cols 64,65.
    {
        const int lx = tid & 63;
        const int ry = tid >> 6;      // wave-uniform row phase 0..3
        #pragma unroll
        for (int c = 0; c < NCH; ++c) {
            const float* sp = src + ((size_t)c * NIMG + n) * plane;
            for (int ly = ry; ly < HTH; ly += 4) {
                const int gy = tile_y - 1 + ly;
                const bool yok = (unsigned)gy < HH;
                const float* rp = sp + (size_t)gy * WW;
                const int gx = tile_x - 1 + lx;
                float v = 0.0f;
                if (yok && (unsigned)gx < WW) v = rp[gx];
                sA[c][ly][lx] = EXP2(0.33333334f * LOG2(v));   // v=0 -> a=0 (correct)
                if (lx < 2) {
                    const int gx2 = gx + 64;
                    float v2 = 0.0f;
                    if (yok && (unsigned)gx2 < WW) v2 = rp[gx2];
                    sA[c][ly][64 + lx] = EXP2(0.33333334f * LOG2(v2));
                }
            }
        }
    }
    __syncthreads();   // only barrier; everything after is read-only LDS

    const int gy  = tile_y + ty;
    const int gx0 = tile_x + tx4;
    float* outp = out + (size_t)n * plane + (size_t)gy * WW + gx0;
    const size_t cstride = (size_t)NIMG * plane;

    float accL[4] = {0.f, 0.f, 0.f, 0.f};
    float accH[4] = {0.f, 0.f, 0.f, 0.f};
    float cA[4], cB[4];

    // edge (0,1): i=0 gets kc=0,ki=1 ; i=1 gets kc=2,ki=3
    edge_conv<0, 1, 2, 3>(sA[0], sA[1], ty, tx4, ker, accL, accH, cA, cB);
    store_out(outp, cA, accL);                       // channel 0 complete

    #pragma unroll
    for (int q = 0; q < 4; ++q) { accL[q] = accH[q]; accH[q] = 0.f; }

    // edge (1,2): i=1 gets kc=4,ki=5 ; i=2 gets kc=6,ki=7
    edge_conv<4, 5, 6, 7>(sA[1], sA[2], ty, tx4, ker, accL, accH, cA, cB);
    store_out(outp + cstride, cA, accL);             // channel 1 complete

    #pragma unroll
    for (int q = 0; q < 4; ++q) { accL[q] = accH[q]; accH[q] = 0.f; }

    // edge (2,3): i=2 gets kc=8,ki=9 ; i=3 gets kc=10,ki=11
    edge_conv<8, 9, 10, 11>(sA[2], sA[3], ty, tx4, ker, accL, accH, cA, cB);
    store_out(outp + 2 * cstride, cA, accL);         // channel 2 complete
    store_out(outp + 3 * cstride, cB, accH);         // channel 3 complete
}

extern "C" void kernel_launch(void* const* d_in, const int* in_sizes, int n_in,
                              void* d_out, int out_size, void* d_ws, size_t ws_size,
                              hipStream_t stream) {
    const float* src = (const float*)d_in[0];
    const float* ker = (const float*)d_in[1];
    float* out = (float*)d_out;

    dim3 grid(WW / TW, HH / TH, NIMG);   // (8, 32, 32) = 8192 blocks
    dim3 block(256);
    bleed_kernel<<<grid, block, 0, stream>>>(src, ker, out);
}

// Round 2
// 400.612 us; speedup vs baseline: 1.6094x; 1.6094x over previous
//
#include <hip/hip_runtime.h>
#include <math.h>

// sources: [4][32][512][512] fp32, kernels: [12][3][3] fp32, out: same as sources
// out_i = s_i - sum_j [ conv(s_j, kc_ij) + conv((s_j^0.5 * s_i)^(2/3), ki_ij) ]
//
// Key identity: with a = v^(1/3):  s = a^3,  (s_j^0.5 * s_i)^(2/3) = a_j * a_i^2.
// => stage ONLY a in LDS (19.5 KB -> up to 8 blocks/CU), no per-pair exp2;
//    raw values reconstructed as a^3 (2 mults).
// Edge sweep (0,1),(1,2),(2,3): each edge computes both directed pairs from one
// pair of row-windows; each channel's output stored from registers when done.
//
// __launch_bounds__(256, 4): 128-VGPR cap. (256,8) capped at 64 VGPRs and
// spilled the conv live set (~90 regs) to scratch -> 1.2 GB of HBM write
// traffic, 3x slowdown (round-1 post-mortem). Do not lower this again.

#define NCH  4
#define NIMG 32
#define HH   512
#define WW   512

#define TW   64
#define TH   16
#define HTWU 66            // used halo width
#define HTW  68            // padded stride (272 B, 16B-aligned rows)
#define HTH  18

#if __has_builtin(__builtin_amdgcn_exp2f)
#define EXP2(x) __builtin_amdgcn_exp2f(x)
#else
#define EXP2(x) exp2f(x)
#endif
#if __has_builtin(__builtin_amdgcn_logf)
#define LOG2(x) __builtin_amdgcn_logf(x)
#else
#define LOG2(x) __log2f(x)
#endif

__device__ __forceinline__ void load_row6(const float* __restrict__ row, float w[6]) {
    const float4 a = *(const float4*)row;          // ds_read_b128 (16B aligned)
    const float2 b = *(const float2*)(row + 4);    // ds_read_b64
    w[0] = a.x; w[1] = a.y; w[2] = a.z; w[3] = a.w; w[4] = b.x; w[5] = b.y;
}

// Edge between channels x and y = x+1 (a-values in Sx, Sy).
//   accX += conv(a_y^3, ker[KCX]) + conv(a_x^2 * a_y, ker[KIX])   (i=x, j=y)
//   accY += conv(a_x^3, ker[KCY]) + conv(a_y^2 * a_x, ker[KIY])   (i=y, j=x)
// cx/cy receive the center-row a values (cols tx4+1..tx4+4) for the epilogue.
template<int KCX, int KIX, int KCY, int KIY>
__device__ __forceinline__ void edge_conv(
    const float (*Sx)[HTW], const float (*Sy)[HTW],
    int ty, int tx4, const float* __restrict__ ker,
    float accX[4], float accY[4], float cx[4], float cy[4])
{
    #pragma unroll
    for (int r = 0; r < 3; ++r) {
        float ax[6], ay[6];
        load_row6(&Sx[ty + r][tx4], ax);
        load_row6(&Sy[ty + r][tx4], ay);
        if (r == 1) {
            #pragma unroll
            for (int q = 0; q < 4; ++q) { cx[q] = ax[q + 1]; cy[q] = ay[q + 1]; }
        }
        float ax2[6], ay2[6];
        #pragma unroll
        for (int q = 0; q < 6; ++q) { ax2[q] = ax[q] * ax[q]; ay2[q] = ay[q] * ay[q]; }

        // direction i=x (neighbor j=y): raw_y = ay^3, inter = ax^2 * ay
        {
            float w[6], t[6];
            #pragma unroll
            for (int q = 0; q < 6; ++q) { w[q] = ay2[q] * ay[q]; t[q] = ax2[q] * ay[q]; }
            #pragma unroll
            for (int q = 0; q < 4; ++q) {
                float s = accX[q];
                #pragma unroll
                for (int dx = 0; dx < 3; ++dx) {
                    s = fmaf(w[q + dx], ker[KCX * 9 + r * 3 + dx], s);
                    s = fmaf(t[q + dx], ker[KIX * 9 + r * 3 + dx], s);
                }
                accX[q] = s;
            }
        }
        // direction i=y (neighbor j=x): raw_x = ax^3, inter = ay^2 * ax
        {
            float w[6], t[6];
            #pragma unroll
            for (int q = 0; q < 6; ++q) { w[q] = ax2[q] * ax[q]; t[q] = ay2[q] * ax[q]; }
            #pragma unroll
            for (int q = 0; q < 4; ++q) {
                float s = accY[q];
                #pragma unroll
                for (int dx = 0; dx < 3; ++dx) {
                    s = fmaf(w[q + dx], ker[KCY * 9 + r * 3 + dx], s);
                    s = fmaf(t[q + dx], ker[KIY * 9 + r * 3 + dx], s);
                }
                accY[q] = s;
            }
        }
    }
}

// out = center^3 - bleed, dwordx4 store
__device__ __forceinline__ void store_out(float* __restrict__ p,
                                          const float c[4], const float a[4]) {
    float4 o;
    o.x = c[0] * c[0] * c[0] - a[0];
    o.y = c[1] * c[1] * c[1] - a[1];
    o.z = c[2] * c[2] * c[2] - a[2];
    o.w = c[3] * c[3] * c[3] - a[3];
    *(float4*)p = o;
}

__global__ __launch_bounds__(256, 4) void bleed_kernel(
    const float* __restrict__ src,   // [4][32][512][512]
    const float* __restrict__ ker,   // [12][3][3]
    float* __restrict__ out)
{
    __shared__ __align__(16) float sA[NCH][HTH][HTW];  // a = v^(1/3)

    const int tid    = threadIdx.x;
    const int tx     = tid & 15;      // col group: cols 4*tx .. 4*tx+3
    const int ty     = tid >> 4;      // row 0..15
    const int tx4    = tx * 4;
    const int tile_x = blockIdx.x * TW;
    const int tile_y = blockIdx.y * TH;
    const int n      = blockIdx.z;    // image index

    const size_t plane = (size_t)HH * WW;

    // ---- stage a = v^(1/3) for all 4 channels, zero-padded halo ----
    // 64-lane rows: lane lx covers col lx; lanes 0,1 also cover cols 64,65.
    {
        const int lx = tid & 63;
        const int ry = tid >> 6;      // wave-uniform row phase 0..3
        #pragma unroll
        for (int c = 0; c < NCH; ++c) {
            const float* sp = src + ((size_t)c * NIMG + n) * plane;
            for (int ly = ry; ly < HTH; ly += 4) {
                const int gy = tile_y - 1 + ly;
                const bool yok = (unsigned)gy < HH;
                const float* rp = sp + (size_t)gy * WW;
                const int gx = tile_x - 1 + lx;
                float v = 0.0f;
                if (yok && (unsigned)gx < WW) v = rp[gx];
                sA[c][ly][lx] = EXP2(0.33333334f * LOG2(v));   // v=0 -> a=0 (correct)
                if (lx < 2) {
                    const int gx2 = gx + 64;
                    float v2 = 0.0f;
                    if (yok && (unsigned)gx2 < WW) v2 = rp[gx2];
                    sA[c][ly][64 + lx] = EXP2(0.33333334f * LOG2(v2));
                }
            }
        }
    }
    __syncthreads();   // only barrier; everything after is read-only LDS

    const int gy  = tile_y + ty;
    const int gx0 = tile_x + tx4;
    float* outp = out + (size_t)n * plane + (size_t)gy * WW + gx0;
    const size_t cstride = (size_t)NIMG * plane;

    float accL[4] = {0.f, 0.f, 0.f, 0.f};
    float accH[4] = {0.f, 0.f, 0.f, 0.f};
    float cA[4], cB[4];

    // edge (0,1): i=0 gets kc=0,ki=1 ; i=1 gets kc=2,ki=3
    edge_conv<0, 1, 2, 3>(sA[0], sA[1], ty, tx4, ker, accL, accH, cA, cB);
    store_out(outp, cA, accL);                       // channel 0 complete

    #pragma unroll
    for (int q = 0; q < 4; ++q) { accL[q] = accH[q]; accH[q] = 0.f; }

    // edge (1,2): i=1 gets kc=4,ki=5 ; i=2 gets kc=6,ki=7
    edge_conv<4, 5, 6, 7>(sA[1], sA[2], ty, tx4, ker, accL, accH, cA, cB);
    store_out(outp + cstride, cA, accL);             // channel 1 complete

    #pragma unroll
    for (int q = 0; q < 4; ++q) { accL[q] = accH[q]; accH[q] = 0.f; }

    // edge (2,3): i=2 gets kc=8,ki=9 ; i=3 gets kc=10,ki=11
    edge_conv<8, 9, 10, 11>(sA[2], sA[3], ty, tx4, ker, accL, accH, cA, cB);
    store_out(outp + 2 * cstride, cA, accL);         // channel 2 complete
    store_out(outp + 3 * cstride, cB, accH);         // channel 3 complete
}

extern "C" void kernel_launch(void* const* d_in, const int* in_sizes, int n_in,
                              void* d_out, int out_size, void* d_ws, size_t ws_size,
                              hipStream_t stream) {
    const float* src = (const float*)d_in[0];
    const float* ker = (const float*)d_in[1];
    float* out = (float*)d_out;

    dim3 grid(WW / TW, HH / TH, NIMG);   // (8, 32, 32) = 8192 blocks
    dim3 block(256);
    bleed_kernel<<<grid, block, 0, stream>>>(src, ker, out);
}